// Round 19
// baseline (157.110 us; speedup 1.0000x reference)
//
#include <hip/hip_runtime.h>
#include <hip/hip_bf16.h>

#define HD 128   // hidden/feature dim
#define NL 7     // label dim
#define BCAP 6144  // per-bucket stage capacity (avg 4082 for E=800K/196 buckets; +50% headroom)

typedef __attribute__((ext_vector_type(8))) short bf16x8;
typedef __attribute__((ext_vector_type(4))) float f32x4;

__device__ __forceinline__ unsigned short f2bf(float f) {
    __hip_bfloat16 b = __float2bfloat16(f);   // RNE
    return *reinterpret_cast<unsigned short*>(&b);
}
__device__ __forceinline__ float bf2f(unsigned short u) {
    unsigned int x = ((unsigned int)u) << 16;
    return __uint_as_float(x);
}

// ---------------- prep: zero gbcur+sums, convert W1/W2 -> bf16 transposed ----------------

__global__ __launch_bounds__(256) void k_prep(int* __restrict__ gbcur, int nb,
                                              float* __restrict__ sums, int m,
                                              const float* __restrict__ W1,
                                              const float* __restrict__ W2,
                                              unsigned short* __restrict__ Wt1,
                                              unsigned short* __restrict__ Wt2) {
    int i = blockIdx.x * 256 + threadIdx.x;
    if (i < nb) gbcur[i] = 0;
    if (i < m) sums[i] = 0.f;
    if (i < HD * HD) {
        int k = i >> 7, nn = i & 127;
        Wt1[nn * HD + k] = f2bf(W1[i]);
        Wt2[nn * HD + k] = f2bf(W2[i]);
    }
}

// ---------------- CSR build phase 1: bucketed partition ----------------

__global__ __launch_bounds__(256) void k_bucket(const int* __restrict__ src,
                                                const int* __restrict__ dst, int E,
                                                int* __restrict__ gbcur,
                                                int* __restrict__ stage, int nb) {
    __shared__ int lh[256];
    __shared__ int gb[256];
    int t = threadIdx.x;
    if (t < nb) lh[t] = 0;
    __syncthreads();

    int e0 = blockIdx.x * 4096;
    int bk[16]; int lr[16]; int rec[16];
    #pragma unroll
    for (int j = 0; j < 16; ++j) {
        int e = e0 + j * 256 + t;
        if (e < E) {
            int d = dst[e];
            int s = src[e];
            bk[j]  = d >> 8;
            rec[j] = ((d & 255) << 16) | s;       // src < 65536
            lr[j]  = atomicAdd(&lh[bk[j]], 1);    // local rank
        } else {
            bk[j] = -1; lr[j] = 0; rec[j] = 0;
        }
    }
    __syncthreads();
    if (t < nb) gb[t] = atomicAdd(&gbcur[t], lh[t]);   // reserve run per bucket
    __syncthreads();
    #pragma unroll
    for (int j = 0; j < 16; ++j) {
        if (bk[j] >= 0) {
            int p = gb[bk[j]] + lr[j];
            if (p < BCAP) stage[bk[j] * BCAP + p] = rec[j];
        }
    }
}

// ---------------- fused: CSR build phase 2 (blocks [0,nb)) ∥ GEMM1 (rest) ----------------

__global__ __launch_bounds__(256) void k_build_gemm1(
        const int* __restrict__ stage, const int* __restrict__ gbcnt,
        int* __restrict__ col, int* __restrict__ row_start,
        float* __restrict__ dinv,
        const float* __restrict__ X, const unsigned short* __restrict__ Wt,
        unsigned short* __restrict__ Y, int n, int nb) {
    __shared__ int rec_s[BCAP];
    __shared__ unsigned short rank_s[BCAP];
    __shared__ int hist[256];
    __shared__ int scan_s[256];
    __shared__ int base_s;
    int t = threadIdx.x;

    if ((int)blockIdx.x < nb) {
        // ---------- build branch ----------
        int b = blockIdx.x;

        int cval = (t < nb) ? gbcnt[t] : 0;
        scan_s[t] = cval;
        __syncthreads();
        #pragma unroll
        for (int off = 1; off < 256; off <<= 1) {
            int v = (t >= off) ? scan_s[t - off] : 0;
            __syncthreads();
            scan_s[t] += v;
            __syncthreads();
        }
        if (t == b) base_s = scan_s[t] - cval;
        if (b == 0 && t == 0) row_start[n] = scan_s[nb - 1];
        __syncthreads();
        int base = base_s;
        int cnt  = min(gbcnt[b], BCAP);
        int node0 = b << 8;

        hist[t] = 0;
        __syncthreads();
        for (int e = t; e < cnt; e += 256) {
            int r = stage[b * BCAP + e];
            rec_s[e] = r;
            rank_s[e] = (unsigned short)atomicAdd(&hist[r >> 16], 1);
        }
        __syncthreads();

        int deg = hist[t];
        int node = node0 + t;
        if (node < n) dinv[node] = 1.0f / sqrtf((float)(deg + 1));  // +1 self loop

        scan_s[t] = deg;
        __syncthreads();
        #pragma unroll
        for (int off = 1; off < 256; off <<= 1) {
            int v = (t >= off) ? scan_s[t - off] : 0;
            __syncthreads();
            scan_s[t] += v;
            __syncthreads();
        }
        int lrs = scan_s[t] - deg;
        hist[t] = lrs;
        if (node < n) row_start[node] = base + lrs;
        __syncthreads();

        for (int e = t; e < cnt; e += 256) {
            int r = rec_s[e];
            col[base + hist[r >> 16] + rank_s[e]] = r & 0xFFFF;
        }
    } else {
        // ---------- GEMM1 branch (f32 in, bf16 out, row-major) ----------
        int wave = t >> 6, lane = t & 63;
        int lm = lane & 15, g = lane >> 4;
        int m0 = ((int)blockIdx.x - nb) * 64 + wave * 16;
        int row = m0 + lm;
        bool rok = row < n;

        f32x4 acc[8] = {};

        #pragma unroll
        for (int kb = 0; kb < 4; ++kb) {
            int k0 = kb * 32 + g * 8;
            bf16x8 a = {0, 0, 0, 0, 0, 0, 0, 0};
            if (rok) {
                const float* xp = X + (size_t)row * HD + k0;
                float4 v0 = *(const float4*)xp;
                float4 v1 = *(const float4*)(xp + 4);
                a[0] = (short)f2bf(v0.x); a[1] = (short)f2bf(v0.y);
                a[2] = (short)f2bf(v0.z); a[3] = (short)f2bf(v0.w);
                a[4] = (short)f2bf(v1.x); a[5] = (short)f2bf(v1.y);
                a[6] = (short)f2bf(v1.z); a[7] = (short)f2bf(v1.w);
            }
            #pragma unroll
            for (int nt = 0; nt < 8; ++nt) {
                int ncol = nt * 16 + lm;
                bf16x8 bfrag = *(const bf16x8*)(Wt + (size_t)ncol * HD + k0);
                acc[nt] = __builtin_amdgcn_mfma_f32_16x16x32_bf16(a, bfrag, acc[nt], 0, 0, 0);
            }
        }

        #pragma unroll
        for (int nt = 0; nt < 8; ++nt) {
            #pragma unroll
            for (int r = 0; r < 4; ++r) {
                int orow = m0 + g * 4 + r;
                if (orow < n) Y[(size_t)orow * HD + nt * 16 + lm] = f2bf(acc[nt][r]);
            }
        }
    }
}

// ---------------- Fused agg1 + GEMM2, 512 threads ----------------
// Block = 16 nodes, 8 waves x 2 nodes serial (2x the waves of the 256-thread
// form: straggler at the barrier is averaged over 8 waves and hidden by other
// blocks). GEMM stage: each wave owns ONE 16x16 N-tile (4 MFMA).

__global__ __launch_bounds__(512) void k_agg_gemm2(
        const unsigned short* __restrict__ hin,   // h1 [n][128] bf16
        const float* __restrict__ dinv,
        const int* __restrict__ row_start,
        const int* __restrict__ col,
        const float* __restrict__ bias,           // b1
        const unsigned short* __restrict__ Wt2,   // [col][k] bf16
        unsigned short* __restrict__ Y,           // z2 [n][128] bf16
        int n) {
    __shared__ __attribute__((aligned(16))) unsigned short arow[16][136];
    int t = threadIdx.x;
    int wave = t >> 6;     // 0..7
    int lane = t & 63;
    int h  = lane >> 5;
    int li = lane & 31;
    int f  = li * 4;
    int node0 = blockIdx.x * 16;

    float4 b = *(const float4*)(bias + f);

    #pragma unroll 1
    for (int i = 0; i < 2; ++i) {
        int vloc = wave * 2 + i;
        int v = node0 + vloc;
        if (v < n) {
            float dv = dinv[v];
            float a0 = 0.f, a1 = 0.f, a2 = 0.f, a3 = 0.f;

            int e  = row_start[v];
            int e1 = row_start[v + 1];

            for (; e + 8 <= e1; e += 8) {
                int s0 = col[e + h];
                int s1 = col[e + h + 2];
                int s2 = col[e + h + 4];
                int s3 = col[e + h + 6];
                float w0 = dinv[s0] * dv, w1 = dinv[s1] * dv;
                float w2 = dinv[s2] * dv, w3 = dinv[s3] * dv;
                ushort4 r0 = *(const ushort4*)(hin + (size_t)s0 * HD + f);
                ushort4 r1 = *(const ushort4*)(hin + (size_t)s1 * HD + f);
                ushort4 r2 = *(const ushort4*)(hin + (size_t)s2 * HD + f);
                ushort4 r3 = *(const ushort4*)(hin + (size_t)s3 * HD + f);
                a0 = fmaf(bf2f(r0.x), w0, a0); a1 = fmaf(bf2f(r0.y), w0, a1);
                a2 = fmaf(bf2f(r0.z), w0, a2); a3 = fmaf(bf2f(r0.w), w0, a3);
                a0 = fmaf(bf2f(r1.x), w1, a0); a1 = fmaf(bf2f(r1.y), w1, a1);
                a2 = fmaf(bf2f(r1.z), w1, a2); a3 = fmaf(bf2f(r1.w), w1, a3);
                a0 = fmaf(bf2f(r2.x), w2, a0); a1 = fmaf(bf2f(r2.y), w2, a1);
                a2 = fmaf(bf2f(r2.z), w2, a2); a3 = fmaf(bf2f(r2.w), w2, a3);
                a0 = fmaf(bf2f(r3.x), w3, a0); a1 = fmaf(bf2f(r3.y), w3, a1);
                a2 = fmaf(bf2f(r3.z), w3, a2); a3 = fmaf(bf2f(r3.w), w3, a3);
            }

            #pragma unroll
            for (int j = 0; j < 4; ++j) {
                int idx = e + h + 2 * j;
                if (idx < e1) {
                    int s = col[idx];
                    float w = dinv[s] * dv;
                    ushort4 r = *(const ushort4*)(hin + (size_t)s * HD + f);
                    a0 = fmaf(bf2f(r.x), w, a0); a1 = fmaf(bf2f(r.y), w, a1);
                    a2 = fmaf(bf2f(r.z), w, a2); a3 = fmaf(bf2f(r.w), w, a3);
                }
            }

            a0 += __shfl_xor(a0, 32);
            a1 += __shfl_xor(a1, 32);
            a2 += __shfl_xor(a2, 32);
            a3 += __shfl_xor(a3, 32);

            if (h == 0) {
                ushort4 sv = *(const ushort4*)(hin + (size_t)v * HD + f);
                float selfw = dv * dv;
                ushort4 o;
                o.x = f2bf(fmaxf(fmaf(bf2f(sv.x), selfw, a0) + b.x, 0.f));
                o.y = f2bf(fmaxf(fmaf(bf2f(sv.y), selfw, a1) + b.y, 0.f));
                o.z = f2bf(fmaxf(fmaf(bf2f(sv.z), selfw, a2) + b.z, 0.f));
                o.w = f2bf(fmaxf(fmaf(bf2f(sv.w), selfw, a3) + b.w, 0.f));
                *(ushort4*)&arow[vloc][f] = o;
            }
        } else if (h == 0) {
            ushort4 z; z.x = z.y = z.z = z.w = 0;
            *(ushort4*)&arow[vloc][f] = z;
        }
    }
    __syncthreads();

    // GEMM: [16 nodes x 128] @ Wt2^T. Wave w owns N-tile w (cols w*16..w*16+15).
    int lm = lane & 15, g = lane >> 4;
    f32x4 acc = {};
    #pragma unroll
    for (int kb = 0; kb < 4; ++kb) {
        int k0 = kb * 32 + g * 8;
        bf16x8 a = *(const bf16x8*)&arow[lm][k0];
        int ncol = wave * 16 + lm;
        bf16x8 bfrag = *(const bf16x8*)(Wt2 + (size_t)ncol * HD + k0);
        acc = __builtin_amdgcn_mfma_f32_16x16x32_bf16(a, bfrag, acc, 0, 0, 0);
    }
    {
        int nc0 = wave * 16;
        #pragma unroll
        for (int r = 0; r < 4; ++r) {
            int v = node0 + g * 4 + r;
            if (v < n) Y[(size_t)v * HD + nc0 + lm] = f2bf(acc[r]);
        }
    }
}

// ---------------- Aggregation layer 2 + LDS-pooled mean-pool, 512 threads ----------
// Block = 32 nodes, 8 waves x 4 nodes serial (2x waves of the 256-thread form).

__global__ __launch_bounds__(512) void k_agg_pool(const unsigned short* __restrict__ hin,
                                                  const float* __restrict__ dinv,
                                                  const int* __restrict__ row_start,
                                                  const int* __restrict__ col,
                                                  const float* __restrict__ bias,
                                                  const int* __restrict__ batch,
                                                  float* __restrict__ sums, int n) {
    __shared__ float lsum[4][HD];
    __shared__ int used[4];
    __shared__ int gbase_s;
    int t = threadIdx.x;

    if (t < 4) used[t] = 0;
    for (int i = t; i < 4 * HD; i += 512) ((float*)lsum)[i] = 0.f;
    int blk0 = blockIdx.x * 32;
    if (t == 0) gbase_s = batch[min(blk0, n - 1)];
    __syncthreads();
    int gbase = gbase_s;

    int wave = t >> 6;     // 0..7
    int lane = t & 63;
    int h  = lane >> 5;
    int li = lane & 31;
    int f  = li * 4;

    int v0 = blk0 + wave * 4;
    int vend = min(v0 + 4, n);

    float4 b = *(const float4*)(bias + f);
    float p0 = 0.f, p1 = 0.f, p2 = 0.f, p3 = 0.f;
    int curg = (v0 < n) ? batch[v0] : -1;

    for (int v = v0; v < vend; ++v) {
        float dv = dinv[v];
        float a0 = 0.f, a1 = 0.f, a2 = 0.f, a3 = 0.f;

        int e  = row_start[v];
        int e1 = row_start[v + 1];

        for (; e + 8 <= e1; e += 8) {
            int s0 = col[e + h];
            int s1 = col[e + h + 2];
            int s2 = col[e + h + 4];
            int s3 = col[e + h + 6];
            float w0 = dinv[s0] * dv, w1 = dinv[s1] * dv;
            float w2 = dinv[s2] * dv, w3 = dinv[s3] * dv;
            ushort4 r0 = *(const ushort4*)(hin + (size_t)s0 * HD + f);
            ushort4 r1 = *(const ushort4*)(hin + (size_t)s1 * HD + f);
            ushort4 r2 = *(const ushort4*)(hin + (size_t)s2 * HD + f);
            ushort4 r3 = *(const ushort4*)(hin + (size_t)s3 * HD + f);
            a0 = fmaf(bf2f(r0.x), w0, a0); a1 = fmaf(bf2f(r0.y), w0, a1);
            a2 = fmaf(bf2f(r0.z), w0, a2); a3 = fmaf(bf2f(r0.w), w0, a3);
            a0 = fmaf(bf2f(r1.x), w1, a0); a1 = fmaf(bf2f(r1.y), w1, a1);
            a2 = fmaf(bf2f(r1.z), w1, a2); a3 = fmaf(bf2f(r1.w), w1, a3);
            a0 = fmaf(bf2f(r2.x), w2, a0); a1 = fmaf(bf2f(r2.y), w2, a1);
            a2 = fmaf(bf2f(r2.z), w2, a2); a3 = fmaf(bf2f(r2.w), w2, a3);
            a0 = fmaf(bf2f(r3.x), w3, a0); a1 = fmaf(bf2f(r3.y), w3, a1);
            a2 = fmaf(bf2f(r3.z), w3, a2); a3 = fmaf(bf2f(r3.w), w3, a3);
        }

        #pragma unroll
        for (int j = 0; j < 4; ++j) {
            int idx = e + h + 2 * j;
            if (idx < e1) {
                int s = col[idx];
                float w = dinv[s] * dv;
                ushort4 r = *(const ushort4*)(hin + (size_t)s * HD + f);
                a0 = fmaf(bf2f(r.x), w, a0); a1 = fmaf(bf2f(r.y), w, a1);
                a2 = fmaf(bf2f(r.z), w, a2); a3 = fmaf(bf2f(r.w), w, a3);
            }
        }

        a0 += __shfl_xor(a0, 32);
        a1 += __shfl_xor(a1, 32);
        a2 += __shfl_xor(a2, 32);
        a3 += __shfl_xor(a3, 32);

        if (h == 0) {
            ushort4 sv = *(const ushort4*)(hin + (size_t)v * HD + f);
            float selfw = dv * dv;
            float ox = fmaxf(fmaf(bf2f(sv.x), selfw, a0) + b.x, 0.f);
            float oy = fmaxf(fmaf(bf2f(sv.y), selfw, a1) + b.y, 0.f);
            float oz = fmaxf(fmaf(bf2f(sv.z), selfw, a2) + b.z, 0.f);
            float ow = fmaxf(fmaf(bf2f(sv.w), selfw, a3) + b.w, 0.f);
            int g = batch[v];
            if (g != curg) {
                int slot = curg - gbase;
                if (slot >= 0 && slot < 4) {
                    atomicAdd(&lsum[slot][f],     p0);
                    atomicAdd(&lsum[slot][f + 1], p1);
                    atomicAdd(&lsum[slot][f + 2], p2);
                    atomicAdd(&lsum[slot][f + 3], p3);
                    used[slot] = 1;
                } else {
                    float* sp = sums + (size_t)curg * HD + f;
                    atomicAdd(sp,     p0);
                    atomicAdd(sp + 1, p1);
                    atomicAdd(sp + 2, p2);
                    atomicAdd(sp + 3, p3);
                }
                p0 = p1 = p2 = p3 = 0.f;
                curg = g;
            }
            p0 += ox; p1 += oy; p2 += oz; p3 += ow;
        }
    }

    if (h == 0 && curg >= 0) {
        int slot = curg - gbase;
        if (slot >= 0 && slot < 4) {
            atomicAdd(&lsum[slot][f],     p0);
            atomicAdd(&lsum[slot][f + 1], p1);
            atomicAdd(&lsum[slot][f + 2], p2);
            atomicAdd(&lsum[slot][f + 3], p3);
            used[slot] = 1;
        } else {
            float* sp = sums + (size_t)curg * HD + f;
            atomicAdd(sp,     p0);
            atomicAdd(sp + 1, p1);
            atomicAdd(sp + 2, p2);
            atomicAdd(sp + 3, p3);
        }
    }
    __syncthreads();

    // block-level flush: 512 threads = 4 slots x 128 features in one pass
    int ff = t & 127;
    int s = t >> 7;
    if (s < 4 && used[s]) {
        atomicAdd(&sums[(size_t)(gbase + s) * HD + ff], lsum[s][ff]);
    }
}

// ---------------- mean + FC ----------------

__global__ __launch_bounds__(128) void k_fc(const float* __restrict__ sums,
                                            const int* __restrict__ batch,
                                            const float* __restrict__ Wfc,
                                            const float* __restrict__ bfc,
                                            float* __restrict__ out, int n) {
    int g = blockIdx.x;
    int t = threadIdx.x;
    __shared__ int slo, shi;
    if (t == 0) {
        int lo = 0, hi = n;
        while (lo < hi) { int m = (lo + hi) >> 1; if (batch[m] < g) lo = m + 1; else hi = m; }
        slo = lo;
        lo = 0; hi = n;
        while (lo < hi) { int m = (lo + hi) >> 1; if (batch[m] < g + 1) lo = m + 1; else hi = m; }
        shi = lo;
    }
    __syncthreads();
    float cnt = (float)(shi - slo);
    __shared__ float sp[HD];
    sp[t] = sums[(size_t)g * HD + t] / fmaxf(cnt, 1.f);
    __syncthreads();
    if (t < NL) {
        float o = bfc[t];
        for (int k = 0; k < HD; ++k) o = fmaf(sp[k], Wfc[k * NL + t], o);
        out[g * NL + t] = o;
    }
}

// ---------------- launch ----------------

extern "C" void kernel_launch(void* const* d_in, const int* in_sizes, int n_in,
                              void* d_out, int out_size, void* d_ws, size_t ws_size,
                              hipStream_t stream) {
    const float* x    = (const float*)d_in[0];
    const int*   ei   = (const int*)d_in[1];
    const int*   batch= (const int*)d_in[2];
    const float* W1   = (const float*)d_in[3];
    const float* b1   = (const float*)d_in[4];
    const float* W2   = (const float*)d_in[5];
    const float* b2   = (const float*)d_in[6];
    const float* Wfc  = (const float*)d_in[7];
    const float* bfc  = (const float*)d_in[8];
    float* out = (float*)d_out;

    int n = in_sizes[0] / HD;       // 50000
    int E = in_sizes[1] / 2;        // 800000
    int G = out_size / NL;          // 128
    const int* srcp = ei;
    const int* dstp = ei + E;

    int nb = (n + 255) >> 8;        // 196 buckets of 256 dst nodes

    char* ws = (char*)d_ws;
    auto align256 = [](size_t v) { return (v + 255) & ~(size_t)255; };
    size_t o = 0;
    int*   row_start = (int*)(ws + o); o = align256(o + (size_t)(n + 1) * 4);
    int*   gbcur     = (int*)(ws + o); o = align256(o + (size_t)nb * 4);
    float* dinv      = (float*)(ws + o); o = align256(o + (size_t)n * 4);
    int*   col       = (int*)(ws + o); o = align256(o + (size_t)E * 4);
    unsigned short* tmp  = (unsigned short*)(ws + o); o = align256(o + (size_t)n * HD * 2);
    unsigned short* tmp2 = (unsigned short*)(ws + o); o = align256(o + (size_t)n * HD * 2);
    int*   stage     = (int*)(ws + o); o = align256(o + (size_t)nb * BCAP * 4);
    float* sums      = (float*)(ws + o); o = align256(o + (size_t)G * HD * 4);
    unsigned short* Wt1 = (unsigned short*)(ws + o); o = align256(o + (size_t)HD * HD * 2);
    unsigned short* Wt2 = (unsigned short*)(ws + o); o = align256(o + (size_t)HD * HD * 2);

    int mZero = G * HD;             // 16384 floats of sums
    k_prep<<<(HD * HD + 255) / 256, 256, 0, stream>>>(gbcur, nb, sums, mZero,
                                                      W1, W2, Wt1, Wt2);

    int nblkC = (E + 4095) / 4096;  // 196
    k_bucket<<<nblkC, 256, 0, stream>>>(srcp, dstp, E, gbcur, stage, nb);

    int gemmBlocks = (n + 63) / 64; // 782
    k_build_gemm1<<<nb + gemmBlocks, 256, 0, stream>>>(stage, gbcur, col, row_start,
                                                       dinv, x, Wt1, tmp, n, nb);

    // fused agg1 + gemm2 (512 threads: 8 waves x 2 nodes)
    k_agg_gemm2<<<(n + 15) / 16, 512, 0, stream>>>(tmp, dinv, row_start, col,
                                                   b1, Wt2, tmp2, n);
    // agg2 + pool (512 threads: 8 waves x 4 nodes)
    k_agg_pool<<<(n + 31) / 32, 512, 0, stream>>>(tmp2, dinv, row_start, col, b2,
                                                  batch, sums, n);

    k_fc<<<G, 128, 0, stream>>>(sums, batch, Wfc, bfc, out, n);
}

// Round 20
// 150.421 us; speedup vs baseline: 1.0445x; 1.0445x over previous
//
#include <hip/hip_runtime.h>
#include <hip/hip_bf16.h>

#define HD 128   // hidden/feature dim
#define NL 7     // label dim
#define BCAP 6144  // per-bucket stage capacity (avg 4082 for E=800K/196 buckets; +50% headroom)

typedef __attribute__((ext_vector_type(8))) short bf16x8;
typedef __attribute__((ext_vector_type(4))) float f32x4;

__device__ __forceinline__ unsigned short f2bf(float f) {
    __hip_bfloat16 b = __float2bfloat16(f);   // RNE
    return *reinterpret_cast<unsigned short*>(&b);
}
__device__ __forceinline__ float bf2f(unsigned short u) {
    unsigned int x = ((unsigned int)u) << 16;
    return __uint_as_float(x);
}

// ---------------- prep: zero gbcur+sums, convert W1/W2 -> bf16 transposed ----------------

__global__ __launch_bounds__(256) void k_prep(int* __restrict__ gbcur, int nb,
                                              float* __restrict__ sums, int m,
                                              const float* __restrict__ W1,
                                              const float* __restrict__ W2,
                                              unsigned short* __restrict__ Wt1,
                                              unsigned short* __restrict__ Wt2) {
    int i = blockIdx.x * 256 + threadIdx.x;
    if (i < nb) gbcur[i] = 0;
    if (i < m) sums[i] = 0.f;
    if (i < HD * HD) {
        int k = i >> 7, nn = i & 127;
        Wt1[nn * HD + k] = f2bf(W1[i]);
        Wt2[nn * HD + k] = f2bf(W2[i]);
    }
}

// ---------------- CSR build phase 1: bucketed partition ----------------

__global__ __launch_bounds__(256) void k_bucket(const int* __restrict__ src,
                                                const int* __restrict__ dst, int E,
                                                int* __restrict__ gbcur,
                                                int* __restrict__ stage, int nb) {
    __shared__ int lh[256];
    __shared__ int gb[256];
    int t = threadIdx.x;
    if (t < nb) lh[t] = 0;
    __syncthreads();

    int e0 = blockIdx.x * 4096;
    int bk[16]; int lr[16]; int rec[16];
    #pragma unroll
    for (int j = 0; j < 16; ++j) {
        int e = e0 + j * 256 + t;
        if (e < E) {
            int d = dst[e];
            int s = src[e];
            bk[j]  = d >> 8;
            rec[j] = ((d & 255) << 16) | s;       // src < 65536
            lr[j]  = atomicAdd(&lh[bk[j]], 1);    // local rank
        } else {
            bk[j] = -1; lr[j] = 0; rec[j] = 0;
        }
    }
    __syncthreads();
    if (t < nb) gb[t] = atomicAdd(&gbcur[t], lh[t]);   // reserve run per bucket
    __syncthreads();
    #pragma unroll
    for (int j = 0; j < 16; ++j) {
        if (bk[j] >= 0) {
            int p = gb[bk[j]] + lr[j];
            if (p < BCAP) stage[bk[j] * BCAP + p] = rec[j];
        }
    }
}

// ---------------- fused: CSR build phase 2 (blocks [0,nb)) ∥ GEMM1 (rest) ----------------
// GEMM1 epilogue row-major (round-14 proven form).

__global__ __launch_bounds__(256) void k_build_gemm1(
        const int* __restrict__ stage, const int* __restrict__ gbcnt,
        int* __restrict__ col, int* __restrict__ row_start,
        float* __restrict__ dinv,
        const float* __restrict__ X, const unsigned short* __restrict__ Wt,
        unsigned short* __restrict__ Y, int n, int nb) {
    __shared__ int rec_s[BCAP];
    __shared__ unsigned short rank_s[BCAP];
    __shared__ int hist[256];
    __shared__ int scan_s[256];
    __shared__ int base_s;
    int t = threadIdx.x;

    if ((int)blockIdx.x < nb) {
        // ---------- build branch ----------
        int b = blockIdx.x;

        int cval = (t < nb) ? gbcnt[t] : 0;
        scan_s[t] = cval;
        __syncthreads();
        #pragma unroll
        for (int off = 1; off < 256; off <<= 1) {
            int v = (t >= off) ? scan_s[t - off] : 0;
            __syncthreads();
            scan_s[t] += v;
            __syncthreads();
        }
        if (t == b) base_s = scan_s[t] - cval;
        if (b == 0 && t == 0) row_start[n] = scan_s[nb - 1];
        __syncthreads();
        int base = base_s;
        int cnt  = min(gbcnt[b], BCAP);
        int node0 = b << 8;

        hist[t] = 0;
        __syncthreads();
        for (int e = t; e < cnt; e += 256) {
            int r = stage[b * BCAP + e];
            rec_s[e] = r;
            rank_s[e] = (unsigned short)atomicAdd(&hist[r >> 16], 1);
        }
        __syncthreads();

        int deg = hist[t];
        int node = node0 + t;
        if (node < n) dinv[node] = 1.0f / sqrtf((float)(deg + 1));  // +1 self loop

        scan_s[t] = deg;
        __syncthreads();
        #pragma unroll
        for (int off = 1; off < 256; off <<= 1) {
            int v = (t >= off) ? scan_s[t - off] : 0;
            __syncthreads();
            scan_s[t] += v;
            __syncthreads();
        }
        int lrs = scan_s[t] - deg;
        hist[t] = lrs;
        if (node < n) row_start[node] = base + lrs;
        __syncthreads();

        for (int e = t; e < cnt; e += 256) {
            int r = rec_s[e];
            col[base + hist[r >> 16] + rank_s[e]] = r & 0xFFFF;
        }
    } else {
        // ---------- GEMM1 branch (f32 in, bf16 out, row-major) ----------
        int wave = t >> 6, lane = t & 63;
        int lm = lane & 15, g = lane >> 4;
        int m0 = ((int)blockIdx.x - nb) * 64 + wave * 16;
        int row = m0 + lm;
        bool rok = row < n;

        f32x4 acc[8] = {};

        #pragma unroll
        for (int kb = 0; kb < 4; ++kb) {
            int k0 = kb * 32 + g * 8;
            bf16x8 a = {0, 0, 0, 0, 0, 0, 0, 0};
            if (rok) {
                const float* xp = X + (size_t)row * HD + k0;
                float4 v0 = *(const float4*)xp;
                float4 v1 = *(const float4*)(xp + 4);
                a[0] = (short)f2bf(v0.x); a[1] = (short)f2bf(v0.y);
                a[2] = (short)f2bf(v0.z); a[3] = (short)f2bf(v0.w);
                a[4] = (short)f2bf(v1.x); a[5] = (short)f2bf(v1.y);
                a[6] = (short)f2bf(v1.z); a[7] = (short)f2bf(v1.w);
            }
            #pragma unroll
            for (int nt = 0; nt < 8; ++nt) {
                int ncol = nt * 16 + lm;
                bf16x8 bfrag = *(const bf16x8*)(Wt + (size_t)ncol * HD + k0);
                acc[nt] = __builtin_amdgcn_mfma_f32_16x16x32_bf16(a, bfrag, acc[nt], 0, 0, 0);
            }
        }

        #pragma unroll
        for (int nt = 0; nt < 8; ++nt) {
            #pragma unroll
            for (int r = 0; r < 4; ++r) {
                int orow = m0 + g * 4 + r;
                if (orow < n) Y[(size_t)orow * HD + nt * 16 + lm] = f2bf(acc[nt][r]);
            }
        }
    }
}

// ---------------- Fused agg1 + GEMM2 (256 threads, round-18 proven) ----------------
// Block = 16 nodes (4 waves x 4 nodes serial). relu'd agg rows -> LDS
// [16][136] bf16, barrier, then 4 waves x 2 N-tiles x 4 MFMA vs L2-resident Wt2.

__global__ __launch_bounds__(256) void k_agg_gemm2(
        const unsigned short* __restrict__ hin,   // h1 [n][128] bf16
        const float* __restrict__ dinv,
        const int* __restrict__ row_start,
        const int* __restrict__ col,
        const float* __restrict__ bias,           // b1
        const unsigned short* __restrict__ Wt2,   // [col][k] bf16
        unsigned short* __restrict__ Y,           // z2 [n][128] bf16
        int n) {
    __shared__ __attribute__((aligned(16))) unsigned short arow[16][136];
    int t = threadIdx.x;
    int wave = t >> 6;
    int lane = t & 63;
    int h  = lane >> 5;
    int li = lane & 31;
    int f  = li * 4;
    int node0 = blockIdx.x * 16;

    float4 b = *(const float4*)(bias + f);

    #pragma unroll 1
    for (int i = 0; i < 4; ++i) {
        int vloc = wave * 4 + i;
        int v = node0 + vloc;
        if (v < n) {
            float dv = dinv[v];
            float a0 = 0.f, a1 = 0.f, a2 = 0.f, a3 = 0.f;

            int e  = row_start[v];
            int e1 = row_start[v + 1];

            for (; e + 8 <= e1; e += 8) {
                int s0 = col[e + h];
                int s1 = col[e + h + 2];
                int s2 = col[e + h + 4];
                int s3 = col[e + h + 6];
                float w0 = dinv[s0] * dv, w1 = dinv[s1] * dv;
                float w2 = dinv[s2] * dv, w3 = dinv[s3] * dv;
                ushort4 r0 = *(const ushort4*)(hin + (size_t)s0 * HD + f);
                ushort4 r1 = *(const ushort4*)(hin + (size_t)s1 * HD + f);
                ushort4 r2 = *(const ushort4*)(hin + (size_t)s2 * HD + f);
                ushort4 r3 = *(const ushort4*)(hin + (size_t)s3 * HD + f);
                a0 = fmaf(bf2f(r0.x), w0, a0); a1 = fmaf(bf2f(r0.y), w0, a1);
                a2 = fmaf(bf2f(r0.z), w0, a2); a3 = fmaf(bf2f(r0.w), w0, a3);
                a0 = fmaf(bf2f(r1.x), w1, a0); a1 = fmaf(bf2f(r1.y), w1, a1);
                a2 = fmaf(bf2f(r1.z), w1, a2); a3 = fmaf(bf2f(r1.w), w1, a3);
                a0 = fmaf(bf2f(r2.x), w2, a0); a1 = fmaf(bf2f(r2.y), w2, a1);
                a2 = fmaf(bf2f(r2.z), w2, a2); a3 = fmaf(bf2f(r2.w), w2, a3);
                a0 = fmaf(bf2f(r3.x), w3, a0); a1 = fmaf(bf2f(r3.y), w3, a1);
                a2 = fmaf(bf2f(r3.z), w3, a2); a3 = fmaf(bf2f(r3.w), w3, a3);
            }

            #pragma unroll
            for (int j = 0; j < 4; ++j) {
                int idx = e + h + 2 * j;
                if (idx < e1) {
                    int s = col[idx];
                    float w = dinv[s] * dv;
                    ushort4 r = *(const ushort4*)(hin + (size_t)s * HD + f);
                    a0 = fmaf(bf2f(r.x), w, a0); a1 = fmaf(bf2f(r.y), w, a1);
                    a2 = fmaf(bf2f(r.z), w, a2); a3 = fmaf(bf2f(r.w), w, a3);
                }
            }

            a0 += __shfl_xor(a0, 32);
            a1 += __shfl_xor(a1, 32);
            a2 += __shfl_xor(a2, 32);
            a3 += __shfl_xor(a3, 32);

            if (h == 0) {
                ushort4 sv = *(const ushort4*)(hin + (size_t)v * HD + f);
                float selfw = dv * dv;
                ushort4 o;
                o.x = f2bf(fmaxf(fmaf(bf2f(sv.x), selfw, a0) + b.x, 0.f));
                o.y = f2bf(fmaxf(fmaf(bf2f(sv.y), selfw, a1) + b.y, 0.f));
                o.z = f2bf(fmaxf(fmaf(bf2f(sv.z), selfw, a2) + b.z, 0.f));
                o.w = f2bf(fmaxf(fmaf(bf2f(sv.w), selfw, a3) + b.w, 0.f));
                *(ushort4*)&arow[vloc][f] = o;
            }
        } else if (h == 0) {
            ushort4 z; z.x = z.y = z.z = z.w = 0;
            *(ushort4*)&arow[vloc][f] = z;
        }
    }
    __syncthreads();

    // GEMM: [16 nodes x 128] @ Wt2^T -> Y rows. Wave w owns N-tiles {2w, 2w+1}.
    int lm = lane & 15, g = lane >> 4;
    f32x4 acc[2] = {};
    #pragma unroll
    for (int kb = 0; kb < 4; ++kb) {
        int k0 = kb * 32 + g * 8;
        bf16x8 a = *(const bf16x8*)&arow[lm][k0];
        #pragma unroll
        for (int j = 0; j < 2; ++j) {
            int ncol = (wave * 2 + j) * 16 + lm;
            bf16x8 bfrag = *(const bf16x8*)(Wt2 + (size_t)ncol * HD + k0);
            acc[j] = __builtin_amdgcn_mfma_f32_16x16x32_bf16(a, bfrag, acc[j], 0, 0, 0);
        }
    }
    #pragma unroll
    for (int j = 0; j < 2; ++j) {
        int nc0 = (wave * 2 + j) * 16;
        #pragma unroll
        for (int r = 0; r < 4; ++r) {
            int v = node0 + g * 4 + r;
            if (v < n) Y[(size_t)v * HD + nc0 + lm] = f2bf(acc[j][r]);
        }
    }
}

// ---------------- Aggregation layer 2 + LDS-pooled mean-pool (256 threads, r16) --------

__global__ __launch_bounds__(256) void k_agg_pool(const unsigned short* __restrict__ hin,
                                                  const float* __restrict__ dinv,
                                                  const int* __restrict__ row_start,
                                                  const int* __restrict__ col,
                                                  const float* __restrict__ bias,
                                                  const int* __restrict__ batch,
                                                  float* __restrict__ sums, int n) {
    __shared__ float lsum[4][HD];
    __shared__ int used[4];
    __shared__ int gbase_s;
    int t = threadIdx.x;

    if (t < 4) used[t] = 0;
    for (int i = t; i < 4 * HD; i += 256) ((float*)lsum)[i] = 0.f;
    int blk0 = blockIdx.x * 32;
    if (t == 0) gbase_s = batch[min(blk0, n - 1)];
    __syncthreads();
    int gbase = gbase_s;

    int wave = t >> 6;
    int lane = t & 63;
    int h  = lane >> 5;
    int li = lane & 31;
    int f  = li * 4;

    int v0 = blk0 + wave * 8;
    int vend = min(v0 + 8, n);

    float4 b = *(const float4*)(bias + f);
    float p0 = 0.f, p1 = 0.f, p2 = 0.f, p3 = 0.f;
    int curg = (v0 < n) ? batch[v0] : -1;

    for (int v = v0; v < vend; ++v) {
        float dv = dinv[v];
        float a0 = 0.f, a1 = 0.f, a2 = 0.f, a3 = 0.f;

        int e  = row_start[v];
        int e1 = row_start[v + 1];

        for (; e + 8 <= e1; e += 8) {
            int s0 = col[e + h];
            int s1 = col[e + h + 2];
            int s2 = col[e + h + 4];
            int s3 = col[e + h + 6];
            float w0 = dinv[s0] * dv, w1 = dinv[s1] * dv;
            float w2 = dinv[s2] * dv, w3 = dinv[s3] * dv;
            ushort4 r0 = *(const ushort4*)(hin + (size_t)s0 * HD + f);
            ushort4 r1 = *(const ushort4*)(hin + (size_t)s1 * HD + f);
            ushort4 r2 = *(const ushort4*)(hin + (size_t)s2 * HD + f);
            ushort4 r3 = *(const ushort4*)(hin + (size_t)s3 * HD + f);
            a0 = fmaf(bf2f(r0.x), w0, a0); a1 = fmaf(bf2f(r0.y), w0, a1);
            a2 = fmaf(bf2f(r0.z), w0, a2); a3 = fmaf(bf2f(r0.w), w0, a3);
            a0 = fmaf(bf2f(r1.x), w1, a0); a1 = fmaf(bf2f(r1.y), w1, a1);
            a2 = fmaf(bf2f(r1.z), w1, a2); a3 = fmaf(bf2f(r1.w), w1, a3);
            a0 = fmaf(bf2f(r2.x), w2, a0); a1 = fmaf(bf2f(r2.y), w2, a1);
            a2 = fmaf(bf2f(r2.z), w2, a2); a3 = fmaf(bf2f(r2.w), w2, a3);
            a0 = fmaf(bf2f(r3.x), w3, a0); a1 = fmaf(bf2f(r3.y), w3, a1);
            a2 = fmaf(bf2f(r3.z), w3, a2); a3 = fmaf(bf2f(r3.w), w3, a3);
        }

        #pragma unroll
        for (int j = 0; j < 4; ++j) {
            int idx = e + h + 2 * j;
            if (idx < e1) {
                int s = col[idx];
                float w = dinv[s] * dv;
                ushort4 r = *(const ushort4*)(hin + (size_t)s * HD + f);
                a0 = fmaf(bf2f(r.x), w, a0); a1 = fmaf(bf2f(r.y), w, a1);
                a2 = fmaf(bf2f(r.z), w, a2); a3 = fmaf(bf2f(r.w), w, a3);
            }
        }

        a0 += __shfl_xor(a0, 32);
        a1 += __shfl_xor(a1, 32);
        a2 += __shfl_xor(a2, 32);
        a3 += __shfl_xor(a3, 32);

        if (h == 0) {
            ushort4 sv = *(const ushort4*)(hin + (size_t)v * HD + f);
            float selfw = dv * dv;
            float ox = fmaxf(fmaf(bf2f(sv.x), selfw, a0) + b.x, 0.f);
            float oy = fmaxf(fmaf(bf2f(sv.y), selfw, a1) + b.y, 0.f);
            float oz = fmaxf(fmaf(bf2f(sv.z), selfw, a2) + b.z, 0.f);
            float ow = fmaxf(fmaf(bf2f(sv.w), selfw, a3) + b.w, 0.f);
            int g = batch[v];
            if (g != curg) {
                int slot = curg - gbase;
                if (slot >= 0 && slot < 4) {
                    atomicAdd(&lsum[slot][f],     p0);
                    atomicAdd(&lsum[slot][f + 1], p1);
                    atomicAdd(&lsum[slot][f + 2], p2);
                    atomicAdd(&lsum[slot][f + 3], p3);
                    used[slot] = 1;
                } else {
                    float* sp = sums + (size_t)curg * HD + f;
                    atomicAdd(sp,     p0);
                    atomicAdd(sp + 1, p1);
                    atomicAdd(sp + 2, p2);
                    atomicAdd(sp + 3, p3);
                }
                p0 = p1 = p2 = p3 = 0.f;
                curg = g;
            }
            p0 += ox; p1 += oy; p2 += oz; p3 += ow;
        }
    }

    if (h == 0 && curg >= 0) {
        int slot = curg - gbase;
        if (slot >= 0 && slot < 4) {
            atomicAdd(&lsum[slot][f],     p0);
            atomicAdd(&lsum[slot][f + 1], p1);
            atomicAdd(&lsum[slot][f + 2], p2);
            atomicAdd(&lsum[slot][f + 3], p3);
            used[slot] = 1;
        } else {
            float* sp = sums + (size_t)curg * HD + f;
            atomicAdd(sp,     p0);
            atomicAdd(sp + 1, p1);
            atomicAdd(sp + 2, p2);
            atomicAdd(sp + 3, p3);
        }
    }
    __syncthreads();

    int ff = t & 127;
    for (int s = t >> 7; s < 4; s += 2) {
        if (used[s]) {
            atomicAdd(&sums[(size_t)(gbase + s) * HD + ff], lsum[s][ff]);
        }
    }
}

// ---------------- mean + FC ----------------

__global__ __launch_bounds__(128) void k_fc(const float* __restrict__ sums,
                                            const int* __restrict__ batch,
                                            const float* __restrict__ Wfc,
                                            const float* __restrict__ bfc,
                                            float* __restrict__ out, int n) {
    int g = blockIdx.x;
    int t = threadIdx.x;
    __shared__ int slo, shi;
    if (t == 0) {
        int lo = 0, hi = n;
        while (lo < hi) { int m = (lo + hi) >> 1; if (batch[m] < g) lo = m + 1; else hi = m; }
        slo = lo;
        lo = 0; hi = n;
        while (lo < hi) { int m = (lo + hi) >> 1; if (batch[m] < g + 1) lo = m + 1; else hi = m; }
        shi = lo;
    }
    __syncthreads();
    float cnt = (float)(shi - slo);
    __shared__ float sp[HD];
    sp[t] = sums[(size_t)g * HD + t] / fmaxf(cnt, 1.f);
    __syncthreads();
    if (t < NL) {
        float o = bfc[t];
        for (int k = 0; k < HD; ++k) o = fmaf(sp[k], Wfc[k * NL + t], o);
        out[g * NL + t] = o;
    }
}

// ---------------- launch ----------------

extern "C" void kernel_launch(void* const* d_in, const int* in_sizes, int n_in,
                              void* d_out, int out_size, void* d_ws, size_t ws_size,
                              hipStream_t stream) {
    const float* x    = (const float*)d_in[0];
    const int*   ei   = (const int*)d_in[1];
    const int*   batch= (const int*)d_in[2];
    const float* W1   = (const float*)d_in[3];
    const float* b1   = (const float*)d_in[4];
    const float* W2   = (const float*)d_in[5];
    const float* b2   = (const float*)d_in[6];
    const float* Wfc  = (const float*)d_in[7];
    const float* bfc  = (const float*)d_in[8];
    float* out = (float*)d_out;

    int n = in_sizes[0] / HD;       // 50000
    int E = in_sizes[1] / 2;        // 800000
    int G = out_size / NL;          // 128
    const int* srcp = ei;
    const int* dstp = ei + E;

    int nb = (n + 255) >> 8;        // 196 buckets of 256 dst nodes

    char* ws = (char*)d_ws;
    auto align256 = [](size_t v) { return (v + 255) & ~(size_t)255; };
    size_t o = 0;
    int*   row_start = (int*)(ws + o); o = align256(o + (size_t)(n + 1) * 4);
    int*   gbcur     = (int*)(ws + o); o = align256(o + (size_t)nb * 4);
    float* dinv      = (float*)(ws + o); o = align256(o + (size_t)n * 4);
    int*   col       = (int*)(ws + o); o = align256(o + (size_t)E * 4);
    unsigned short* tmp  = (unsigned short*)(ws + o); o = align256(o + (size_t)n * HD * 2);
    unsigned short* tmp2 = (unsigned short*)(ws + o); o = align256(o + (size_t)n * HD * 2);
    int*   stage     = (int*)(ws + o); o = align256(o + (size_t)nb * BCAP * 4);
    float* sums      = (float*)(ws + o); o = align256(o + (size_t)G * HD * 4);
    unsigned short* Wt1 = (unsigned short*)(ws + o); o = align256(o + (size_t)HD * HD * 2);
    unsigned short* Wt2 = (unsigned short*)(ws + o); o = align256(o + (size_t)HD * HD * 2);

    int mZero = G * HD;             // 16384 floats of sums
    k_prep<<<(HD * HD + 255) / 256, 256, 0, stream>>>(gbcur, nb, sums, mZero,
                                                      W1, W2, Wt1, Wt2);

    int nblkC = (E + 4095) / 4096;  // 196
    k_bucket<<<nblkC, 256, 0, stream>>>(srcp, dstp, E, gbcur, stage, nb);

    int gemmBlocks = (n + 63) / 64; // 782
    k_build_gemm1<<<nb + gemmBlocks, 256, 0, stream>>>(stage, gbcur, col, row_start,
                                                       dinv, x, Wt1, tmp, n, nb);

    // fused agg1 + gemm2: reads h1 (tmp), writes z2 (tmp2)
    k_agg_gemm2<<<(n + 15) / 16, 256, 0, stream>>>(tmp, dinv, row_start, col,
                                                   b1, Wt2, tmp2, n);
    // agg2 + pool (reads z2)
    k_agg_pool<<<(n + 31) / 32, 256, 0, stream>>>(tmp2, dinv, row_start, col, b2,
                                                  batch, sums, n);

    k_fc<<<G, 128, 0, stream>>>(sums, batch, Wfc, bfc, out, n);
}